// Round 1
// baseline (998.597 us; speedup 1.0000x reference)
//
#include <hip/hip_runtime.h>

#define L_ 2
#define MODS_ 3
#define D_ 512
#define R_ 32
#define B_ 16
#define T_ 512
#define BT_ (B_*T_)   /* 8192 tokens per modality */
#define BETA_ 0.1f

// ---------------------------------------------------------------------------
// K1: projections -> u = (Xq1+b)(Xk1+b), v = (Xq2+b)(Xk2+b)
// GEMM [64 tok x 512] @ [512 x 128] per block; cols: [q1|q2|k1|k2] (32 each)
// grid (BT_/64, MODS_), block 256
// ---------------------------------------------------------------------------
__global__ __launch_bounds__(256) void k_proj_uv(
    const float* __restrict__ X,
    const float* __restrict__ Wq1, const float* __restrict__ bq1,
    const float* __restrict__ Wq2, const float* __restrict__ bq2,
    const float* __restrict__ Wk1, const float* __restrict__ bk1,
    const float* __restrict__ Wk2, const float* __restrict__ bk2,
    float* __restrict__ U, float* __restrict__ V, int li)
{
    const int tid  = threadIdx.x;
    const int m    = blockIdx.y;
    const int tok0 = blockIdx.x * 64;

    __shared__ float As[64][17];    // X tile [64 tok][16 k], padded
    __shared__ float Bs[16][128];   // W tile [16 k][128 cols]

    float acc[8][4];
    #pragma unroll
    for (int i = 0; i < 8; ++i)
        acc[i][0] = acc[i][1] = acc[i][2] = acc[i][3] = 0.f;

    const int r = tid & 31;         // output col within a projection
    const int g = tid >> 5;         // token group (8 tokens each)

    // B staging: row bk (k), col base bc
    const int bk  = tid >> 4;
    const int bc  = (tid & 15) * 8;
    const int bp  = bc >> 5;
    const int brr = bc & 31;
    const float* Wsel = (bp == 0) ? Wq1 : (bp == 1) ? Wq2 : (bp == 2) ? Wk1 : Wk2;
    const size_t wbase = ((size_t)(li * MODS_ + m)) * D_ * R_;

    // A staging
    const int at = tid >> 2;
    const int ad = (tid & 3) * 4;
    const size_t xrow = ((size_t)m * BT_ + tok0 + at) * D_;

    for (int k0 = 0; k0 < D_; k0 += 16) {
        const float4 xv = *(const float4*)&X[xrow + k0 + ad];
        const float4 w0 = *(const float4*)&Wsel[wbase + (size_t)(k0 + bk) * R_ + brr];
        const float4 w1 = *(const float4*)&Wsel[wbase + (size_t)(k0 + bk) * R_ + brr + 4];
        __syncthreads();
        As[at][ad + 0] = xv.x; As[at][ad + 1] = xv.y;
        As[at][ad + 2] = xv.z; As[at][ad + 3] = xv.w;
        *(float4*)&Bs[bk][bc]     = w0;
        *(float4*)&Bs[bk][bc + 4] = w1;
        __syncthreads();
        #pragma unroll
        for (int kk = 0; kk < 16; ++kk) {
            const float b0 = Bs[kk][r];
            const float b1 = Bs[kk][32 + r];
            const float b2 = Bs[kk][64 + r];
            const float b3 = Bs[kk][96 + r];
            #pragma unroll
            for (int i = 0; i < 8; ++i) {
                const float a = As[g * 8 + i][kk];
                acc[i][0] += a * b0; acc[i][1] += a * b1;
                acc[i][2] += a * b2; acc[i][3] += a * b3;
            }
        }
    }

    const size_t pb = (size_t)(li * MODS_ + m) * R_ + r;
    const float vq1 = bq1[pb], vq2 = bq2[pb], vk1 = bk1[pb], vk2 = bk2[pb];
    #pragma unroll
    for (int i = 0; i < 8; ++i) {
        const int tok = tok0 + g * 8 + i;
        const float q1v = acc[i][0] + vq1;
        const float q2v = acc[i][1] + vq2;
        const float k1v = acc[i][2] + vk1;
        const float k2v = acc[i][3] + vk2;
        const size_t o = ((size_t)m * BT_ + tok) * R_ + r;
        U[o] = q1v * k1v;
        V[o] = q2v * k2v;
    }
}

// ---------------------------------------------------------------------------
// K2: Mqk[m,b] = (1/T) * U^T V   (R x R), per (m,b)
// grid (MODS_*B_), block 256
// ---------------------------------------------------------------------------
__global__ __launch_bounds__(256) void k_mqk(const float* __restrict__ U,
                                             const float* __restrict__ V,
                                             float* __restrict__ Mqk)
{
    const int tid = threadIdx.x;
    const int mb  = blockIdx.x;

    __shared__ float Us[64][32];
    __shared__ float Vs[64][32];

    const int l = tid & 31;
    const int g = tid >> 5;
    float acc[4] = {0.f, 0.f, 0.f, 0.f};

    const float* Ub = U + (size_t)mb * T_ * R_;
    const float* Vb = V + (size_t)mb * T_ * R_;
    const int st = tid >> 2, sc = (tid & 3) * 8;

    for (int t0 = 0; t0 < T_; t0 += 64) {
        const float4 u0 = *(const float4*)&Ub[(size_t)(t0 + st) * R_ + sc];
        const float4 u1 = *(const float4*)&Ub[(size_t)(t0 + st) * R_ + sc + 4];
        const float4 v0 = *(const float4*)&Vb[(size_t)(t0 + st) * R_ + sc];
        const float4 v1 = *(const float4*)&Vb[(size_t)(t0 + st) * R_ + sc + 4];
        __syncthreads();
        *(float4*)&Us[st][sc]     = u0; *(float4*)&Us[st][sc + 4] = u1;
        *(float4*)&Vs[st][sc]     = v0; *(float4*)&Vs[st][sc + 4] = v1;
        __syncthreads();
        #pragma unroll
        for (int tt = 0; tt < 64; ++tt) {
            const float v = Vs[tt][l];
            #pragma unroll
            for (int i = 0; i < 4; ++i) acc[i] += Us[tt][g + 8 * i] * v;
        }
    }
    #pragma unroll
    for (int i = 0; i < 4; ++i)
        Mqk[(size_t)mb * (R_ * R_) + (size_t)(g + 8 * i) * R_ + l] = acc[i] * (1.0f / T_);
}

// ---------------------------------------------------------------------------
// K3: P_j[b] = Mqk[a][b] @ Mqk[c][b]   (R x R)
//  j=0 -> Mqk[1]@Mqk[2]; j=1 -> Mqk[0]@Mqk[2]; j=2 -> Mqk[0]@Mqk[1]
// grid (MODS_, B_), block 256
// ---------------------------------------------------------------------------
__global__ __launch_bounds__(256) void k_pmat(const float* __restrict__ Mqk,
                                              float* __restrict__ P)
{
    const int tid = threadIdx.x;
    const int j = blockIdx.x, b = blockIdx.y;
    const int a = (j == 0) ? 1 : 0;
    const int c = (j == 2) ? 1 : 2;

    __shared__ float As[32][32];
    __shared__ float Cs[32][32];

    const float4 av = *(const float4*)&Mqk[((size_t)(a * B_ + b)) * 1024 + tid * 4];
    const float4 cv = *(const float4*)&Mqk[((size_t)(c * B_ + b)) * 1024 + tid * 4];
    *(float4*)&(((float*)As)[tid * 4]) = av;
    *(float4*)&(((float*)Cs)[tid * 4]) = cv;
    __syncthreads();

    const int o = tid & 31, g = tid >> 5;
    float acc[4] = {0.f, 0.f, 0.f, 0.f};
    #pragma unroll
    for (int l = 0; l < 32; ++l) {
        const float cvv = Cs[l][o];
        #pragma unroll
        for (int i = 0; i < 4; ++i) acc[i] += As[g + 8 * i][l] * cvv;
    }
    #pragma unroll
    for (int i = 0; i < 4; ++i)
        P[((size_t)(j * B_ + b)) * 1024 + (size_t)(g + 8 * i) * R_ + o] = acc[i];
}

// ---------------------------------------------------------------------------
// K4: w[j,b,t,:] = v[j,b,t,:] @ P_j[b]   (row-vector x R x R)
// grid (BT_/128, MODS_), block 256
// ---------------------------------------------------------------------------
__global__ __launch_bounds__(256) void k_wvec(const float* __restrict__ V,
                                              const float* __restrict__ P,
                                              float* __restrict__ W2)
{
    const int tid  = threadIdx.x;
    const int m    = blockIdx.y;
    const int tok0 = blockIdx.x * 128;
    const int b    = tok0 / T_;

    __shared__ float Ps[32][32];
    __shared__ float Vs[128][32];

    *(float4*)&(((float*)Ps)[tid * 4]) =
        *(const float4*)&P[((size_t)(m * B_ + b)) * 1024 + tid * 4];

    const int st = tid >> 1, sc = (tid & 1) * 16;
    const float* Vb = V + ((size_t)m * BT_ + tok0) * R_;
    #pragma unroll
    for (int q = 0; q < 4; ++q)
        *(float4*)&Vs[st][sc + q * 4] = *(const float4*)&Vb[(size_t)st * R_ + sc + q * 4];
    __syncthreads();

    const int o = tid & 31, g = tid >> 5;
    float* W2b = W2 + ((size_t)m * BT_ + tok0) * R_;
    #pragma unroll
    for (int i = 0; i < 16; ++i) {
        const int t = g * 16 + i;
        float acc = 0.f;
        #pragma unroll
        for (int l = 0; l < 32; ++l) acc += Vs[t][l] * Ps[l][o];
        W2b[(size_t)t * R_ + o] = acc;
    }
}

// ---------------------------------------------------------------------------
// K5: final GEMM + residual, in-place on X:
//   proj[t,d] = sum_{k,o} u[t,k] w[t,o] Watt[k*32+o, d] + batt[d]
//   X[t,d]    = proj*X + BETA*X
// A-tile generated on the fly from u,w (rank-1 per token).
// grid (BT_/64, D_/64, MODS_), block 256
// ---------------------------------------------------------------------------
__global__ __launch_bounds__(256) void k_gemm2(
    const float* __restrict__ U, const float* __restrict__ W2,
    const float* __restrict__ Watt, const float* __restrict__ batt,
    float* __restrict__ X, int li)
{
    const int tid  = threadIdx.x;
    const int j    = blockIdx.z;
    const int tok0 = blockIdx.x * 64;
    const int d0   = blockIdx.y * 64;

    __shared__ float us[64][36];
    __shared__ float ws[64][36];
    __shared__ float As[64][36];
    __shared__ float Bs[32][68];

    // stage u, w for these 64 tokens (all 32 of each)
    {
        const int st = tid >> 2, sc = (tid & 3) * 8;
        const size_t ub = ((size_t)j * BT_ + tok0 + st) * R_ + sc;
        *(float4*)&us[st][sc]     = *(const float4*)&U[ub];
        *(float4*)&us[st][sc + 4] = *(const float4*)&U[ub + 4];
        *(float4*)&ws[st][sc]     = *(const float4*)&W2[ub];
        *(float4*)&ws[st][sc + 4] = *(const float4*)&W2[ub + 4];
    }

    float acc[4][4];
    #pragma unroll
    for (int i = 0; i < 4; ++i)
        acc[i][0] = acc[i][1] = acc[i][2] = acc[i][3] = 0.f;

    const int ct  = tid >> 4;         // token group (4 tokens)
    const int cc  = (tid & 15) * 4;   // col base (4 cols)
    const int brr = tid >> 3;         // Bs staging row 0..31
    const int bc2 = (tid & 7) * 8;    // Bs staging col
    const int at  = tid >> 2;         // As staging row 0..63
    const int ac  = (tid & 3) * 8;    // As staging col

    const float* Wb = Watt + ((size_t)(li * MODS_ + j) * 1024) * D_ + d0;

    for (int k = 0; k < 32; ++k) {
        const float4 b0 = *(const float4*)&Wb[(size_t)(k * 32 + brr) * D_ + bc2];
        const float4 b1 = *(const float4*)&Wb[(size_t)(k * 32 + brr) * D_ + bc2 + 4];
        __syncthreads();   // previous iteration's compute done
        *(float4*)&Bs[brr][bc2]     = b0;
        *(float4*)&Bs[brr][bc2 + 4] = b1;
        {
            const float uval = us[at][k];
            const float4 w0 = *(const float4*)&ws[at][ac];
            const float4 w1 = *(const float4*)&ws[at][ac + 4];
            float4 a0, a1;
            a0.x = uval * w0.x; a0.y = uval * w0.y; a0.z = uval * w0.z; a0.w = uval * w0.w;
            a1.x = uval * w1.x; a1.y = uval * w1.y; a1.z = uval * w1.z; a1.w = uval * w1.w;
            *(float4*)&As[at][ac]     = a0;
            *(float4*)&As[at][ac + 4] = a1;
        }
        __syncthreads();   // staging visible
        #pragma unroll
        for (int o = 0; o < 32; ++o) {
            const float4 bv = *(const float4*)&Bs[o][cc];
            const float a0 = As[ct * 4 + 0][o];
            const float a1 = As[ct * 4 + 1][o];
            const float a2 = As[ct * 4 + 2][o];
            const float a3 = As[ct * 4 + 3][o];
            acc[0][0] += a0 * bv.x; acc[0][1] += a0 * bv.y; acc[0][2] += a0 * bv.z; acc[0][3] += a0 * bv.w;
            acc[1][0] += a1 * bv.x; acc[1][1] += a1 * bv.y; acc[1][2] += a1 * bv.z; acc[1][3] += a1 * bv.w;
            acc[2][0] += a2 * bv.x; acc[2][1] += a2 * bv.y; acc[2][2] += a2 * bv.z; acc[2][3] += a2 * bv.w;
            acc[3][0] += a3 * bv.x; acc[3][1] += a3 * bv.y; acc[3][2] += a3 * bv.z; acc[3][3] += a3 * bv.w;
        }
    }

    // epilogue: add bias, residual combine, in-place store
    const float4 bt4 = *(const float4*)&batt[(size_t)(li * MODS_ + j) * D_ + d0 + cc];
    #pragma unroll
    for (int i = 0; i < 4; ++i) {
        const size_t xi = ((size_t)j * BT_ + tok0 + ct * 4 + i) * D_ + d0 + cc;
        const float4 xv = *(const float4*)&X[xi];
        float4 ov;
        ov.x = (acc[i][0] + bt4.x) * xv.x + BETA_ * xv.x;
        ov.y = (acc[i][1] + bt4.y) * xv.y + BETA_ * xv.y;
        ov.z = (acc[i][2] + bt4.z) * xv.z + BETA_ * xv.z;
        ov.w = (acc[i][3] + bt4.w) * xv.w + BETA_ * xv.w;
        *(float4*)&X[xi] = ov;
    }
}

// ---------------------------------------------------------------------------
extern "C" void kernel_launch(void* const* d_in, const int* in_sizes, int n_in,
                              void* d_out, int out_size, void* d_ws, size_t ws_size,
                              hipStream_t stream)
{
    const float* x_a  = (const float*)d_in[0];
    const float* x_t  = (const float*)d_in[1];
    const float* x_v  = (const float*)d_in[2];
    const float* Wq1  = (const float*)d_in[3];
    const float* bq1  = (const float*)d_in[4];
    const float* Wq2  = (const float*)d_in[5];
    const float* bq2  = (const float*)d_in[6];
    const float* Wk1  = (const float*)d_in[7];
    const float* bk1  = (const float*)d_in[8];
    const float* Wk2  = (const float*)d_in[9];
    const float* bk2  = (const float*)d_in[10];
    const float* Watt = (const float*)d_in[11];
    const float* batt = (const float*)d_in[12];

    float* X  = (float*)d_out;                       // [3][B*T][D], in-place across layers
    float* U  = (float*)d_ws;                        // [3][B*T][R]
    float* V  = U  + (size_t)MODS_ * BT_ * R_;       // [3][B*T][R]
    float* W2 = V  + (size_t)MODS_ * BT_ * R_;       // [3][B*T][R]
    float* Mq = W2 + (size_t)MODS_ * BT_ * R_;       // [3*B][R*R]
    float* P  = Mq + (size_t)MODS_ * B_ * R_ * R_;   // [3*B][R*R]

    const size_t modbytes = (size_t)BT_ * D_ * sizeof(float);
    hipMemcpyAsync(X,                      x_a, modbytes, hipMemcpyDeviceToDevice, stream);
    hipMemcpyAsync(X + (size_t)BT_ * D_,   x_t, modbytes, hipMemcpyDeviceToDevice, stream);
    hipMemcpyAsync(X + (size_t)2 * BT_ * D_, x_v, modbytes, hipMemcpyDeviceToDevice, stream);

    for (int li = 0; li < L_; ++li) {
        k_proj_uv<<<dim3(BT_ / 64, MODS_), 256, 0, stream>>>(
            X, Wq1, bq1, Wq2, bq2, Wk1, bk1, Wk2, bk2, U, V, li);
        k_mqk<<<dim3(MODS_ * B_), 256, 0, stream>>>(U, V, Mq);
        k_pmat<<<dim3(MODS_, B_), 256, 0, stream>>>(Mq, P);
        k_wvec<<<dim3(BT_ / 128, MODS_), 256, 0, stream>>>(V, P, W2);
        k_gemm2<<<dim3(BT_ / 64, D_ / 64, MODS_), 256, 0, stream>>>(
            U, W2, Watt, batt, X, li);
    }
}

// Round 3
// 318.301 us; speedup vs baseline: 3.1373x; 3.1373x over previous
//
#include <hip/hip_runtime.h>

#define L_ 2
#define MODS_ 3
#define D_ 512
#define R_ 32
#define B_ 16
#define T_ 512
#define BT_ (B_*T_)   /* 8192 tokens per modality */
#define BETA_ 0.1f

typedef _Float16 h8 __attribute__((ext_vector_type(8)));
typedef __fp16   fp16x2 __attribute__((ext_vector_type(2)));
typedef float f32x16 __attribute__((ext_vector_type(16)));

typedef __attribute__((address_space(3))) unsigned int lds_u32;
typedef __attribute__((address_space(1))) const unsigned int glb_u32;

__device__ __forceinline__ void gload_lds16(const uint4* gsrc, uint4* ldst){
    __builtin_amdgcn_global_load_lds((glb_u32*)gsrc, (lds_u32*)ldst, 16, 0, 0);
}

__device__ __forceinline__ h8 mk_h8(float f0,float f1,float f2,float f3,
                                    float f4,float f5,float f6,float f7){
    union { h8 v; fp16x2 p[4]; } r;
    r.p[0] = __builtin_amdgcn_cvt_pkrtz(f0,f1);
    r.p[1] = __builtin_amdgcn_cvt_pkrtz(f2,f3);
    r.p[2] = __builtin_amdgcn_cvt_pkrtz(f4,f5);
    r.p[3] = __builtin_amdgcn_cvt_pkrtz(f6,f7);
    return r.v;
}

// ---------------------------------------------------------------------------
// k_cvt: weights -> fragment-major f16.
// WattF frag: per (li,j): [s:32][nb:16][kh:2][lane:64][j8:8]
//   elem = Watt[ko = s*32 + kh*16 + (lane>>5)*8 + j8][nb*32 + (lane&31)]
// WprojF frag: per (li,m): [s:32][nb:4][lane:64][j8:8], cols = [q1|k1|q2|k2]
//   elem = Wsel(nb)[k = s*16 + (lane>>5)*8 + j8][lane&31]
// ---------------------------------------------------------------------------
__global__ __launch_bounds__(256) void k_cvt(
    const float* __restrict__ Watt,
    const float* __restrict__ Wq1, const float* __restrict__ Wk1,
    const float* __restrict__ Wq2, const float* __restrict__ Wk2,
    uint4* __restrict__ WattF, uint4* __restrict__ WprojF)
{
    const int t = blockIdx.x*256 + threadIdx.x;
    const int NWATT = 6*32*16*2*64;   // 393216 (frag,lane) units
    if (t < NWATT) {
        const int lane = t & 63, f = t >> 6;
        const int kh = f & 1, nb = (f>>1)&15, s = (f>>5)&31, lj = f>>10;
        const int col  = nb*32 + (lane&31);
        const int row0 = s*32 + kh*16 + (lane>>5)*8;
        const float* src = Watt + ((size_t)lj*1024)*D_ + col;
        union { uint4 q; unsigned short us[8]; } o;
        #pragma unroll
        for (int i=0;i<8;i++){
            float x = src[(size_t)(row0+i)*D_];
            o.us[i] = __builtin_bit_cast(unsigned short, (_Float16)x);
        }
        WattF[t] = o.q;
    } else {
        const int t2 = t - NWATT;           // < 49152
        const int lane = t2 & 63, f = t2 >> 6;
        const int nb = f & 3, s = (f>>2)&31, lm = f>>7;
        const float* Ws = (nb==0)?Wq1:(nb==1)?Wk1:(nb==2)?Wq2:Wk2;
        const int r  = lane&31;
        const int k0 = s*16 + (lane>>5)*8;
        const float* src = Ws + ((size_t)lm*D_)*R_ + r;
        union { uint4 q; unsigned short us[8]; } o;
        #pragma unroll
        for (int i=0;i<8;i++){
            float x = src[(size_t)(k0+i)*R_];
            o.us[i] = __builtin_bit_cast(unsigned short, (_Float16)x);
        }
        WprojF[t2] = o.q;
    }
}

// ---------------------------------------------------------------------------
// k_proj_mfma: [q1|k1|q2|k2] = X @ Wcat (f16 MFMA), then U=q1*k1, V=q2*k2.
// Block: 64 tok x 128 cols, 4 waves = (tokg 0/1) x (colh 0/1, 64 cols each).
// grid (BT/64, MODS), block 256
// ---------------------------------------------------------------------------
__global__ __launch_bounds__(256) void k_proj_mfma(
    const float* __restrict__ X, const uint4* __restrict__ WprojF,
    const float* __restrict__ bq1, const float* __restrict__ bq2,
    const float* __restrict__ bk1, const float* __restrict__ bk2,
    float* __restrict__ U, float* __restrict__ V, int li)
{
    __shared__ uint4 sm[2][256];   // 2 x 4KB B-tiles
    const int tid = threadIdx.x;
    const int wid = tid>>6, lane = tid&63;
    const int lh = lane>>5, lr = lane&31;
    const int tokg = wid&1, colh = wid>>1;
    const int m = blockIdx.y;
    const int tok0 = blockIdx.x*64;
    const int lm = li*MODS_ + m;
    const int t = tok0 + tokg*32 + lr;

    const uint4* src  = WprojF + (size_t)lm*8192;   // 128 frags * 64 u4
    const float* Xrow = X + ((size_t)m*BT_ + t)*D_;

    f32x16 acc0, acc1;
    #pragma unroll
    for (int i=0;i<16;i++){ acc0[i]=0.f; acc1[i]=0.f; }

    gload_lds16(src + tid, &sm[0][wid*64]);
    __syncthreads();

    float4 x0 = *(const float4*)&Xrow[lh*8];
    float4 x1 = *(const float4*)&Xrow[lh*8+4];

    #pragma unroll
    for (int s=0;s<32;s++){
        const int cur = s&1;
        float4 nx0, nx1;
        if (s<31){
            gload_lds16(src + (s+1)*256 + tid, &sm[cur^1][wid*64]);
            nx0 = *(const float4*)&Xrow[(s+1)*16 + lh*8];
            nx1 = *(const float4*)&Xrow[(s+1)*16 + lh*8 + 4];
        }
        h8 a  = mk_h8(x0.x,x0.y,x0.z,x0.w, x1.x,x1.y,x1.z,x1.w);
        h8 b0 = __builtin_bit_cast(h8, sm[cur][(colh*2+0)*64 + lane]);
        h8 b1 = __builtin_bit_cast(h8, sm[cur][(colh*2+1)*64 + lane]);
        acc0 = __builtin_amdgcn_mfma_f32_32x32x16_f16(a, b0, acc0, 0,0,0);
        acc1 = __builtin_amdgcn_mfma_f32_32x32x16_f16(a, b1, acc1, 0,0,0);
        __syncthreads();
        if (s<31){ x0 = nx0; x1 = nx1; }
    }

    const float bA = (colh==0 ? bq1 : bq2)[lm*R_ + lr];
    const float bB = (colh==0 ? bk1 : bk2)[lm*R_ + lr];
    float* Out = (colh==0 ? U : V);
    #pragma unroll
    for (int reg=0;reg<16;reg++){
        const int row = (reg&3) + 8*(reg>>2) + 4*lh;
        const int tt  = tok0 + tokg*32 + row;
        Out[((size_t)m*BT_ + tt)*R_ + lr] = (acc0[reg]+bA)*(acc1[reg]+bB);
    }
}

// ---------------------------------------------------------------------------
// k_mqk: Mqk[m,b] = (1/T) U^T V (fp32)
// ---------------------------------------------------------------------------
__global__ __launch_bounds__(256) void k_mqk(const float* __restrict__ U,
                                             const float* __restrict__ V,
                                             float* __restrict__ Mqk)
{
    const int tid = threadIdx.x;
    const int mb  = blockIdx.x;

    __shared__ float Us[64][32];
    __shared__ float Vs[64][32];

    const int l = tid & 31;
    const int g = tid >> 5;
    float acc[4] = {0.f, 0.f, 0.f, 0.f};

    const float* Ub = U + (size_t)mb * T_ * R_;
    const float* Vb = V + (size_t)mb * T_ * R_;
    const int st = tid >> 2, sc = (tid & 3) * 8;

    for (int t0 = 0; t0 < T_; t0 += 64) {
        const float4 u0 = *(const float4*)&Ub[(size_t)(t0 + st) * R_ + sc];
        const float4 u1 = *(const float4*)&Ub[(size_t)(t0 + st) * R_ + sc + 4];
        const float4 v0 = *(const float4*)&Vb[(size_t)(t0 + st) * R_ + sc];
        const float4 v1 = *(const float4*)&Vb[(size_t)(t0 + st) * R_ + sc + 4];
        __syncthreads();
        *(float4*)&Us[st][sc]     = u0; *(float4*)&Us[st][sc + 4] = u1;
        *(float4*)&Vs[st][sc]     = v0; *(float4*)&Vs[st][sc + 4] = v1;
        __syncthreads();
        #pragma unroll
        for (int tt = 0; tt < 64; ++tt) {
            const float v = Vs[tt][l];
            #pragma unroll
            for (int i = 0; i < 4; ++i) acc[i] += Us[tt][g + 8 * i] * v;
        }
    }
    #pragma unroll
    for (int i = 0; i < 4; ++i)
        Mqk[(size_t)mb * (R_ * R_) + (size_t)(g + 8 * i) * R_ + l] = acc[i] * (1.0f / T_);
}

// ---------------------------------------------------------------------------
// k_pmat (fp32)
// ---------------------------------------------------------------------------
__global__ __launch_bounds__(256) void k_pmat(const float* __restrict__ Mqk,
                                              float* __restrict__ P)
{
    const int tid = threadIdx.x;
    const int j = blockIdx.x, b = blockIdx.y;
    const int a = (j == 0) ? 1 : 0;
    const int c = (j == 2) ? 1 : 2;

    __shared__ float As[32][32];
    __shared__ float Cs[32][32];

    const float4 av = *(const float4*)&Mqk[((size_t)(a * B_ + b)) * 1024 + tid * 4];
    const float4 cv = *(const float4*)&Mqk[((size_t)(c * B_ + b)) * 1024 + tid * 4];
    *(float4*)&(((float*)As)[tid * 4]) = av;
    *(float4*)&(((float*)Cs)[tid * 4]) = cv;
    __syncthreads();

    const int o = tid & 31, g = tid >> 5;
    float acc[4] = {0.f, 0.f, 0.f, 0.f};
    #pragma unroll
    for (int l = 0; l < 32; ++l) {
        const float cvv = Cs[l][o];
        #pragma unroll
        for (int i = 0; i < 4; ++i) acc[i] += As[g + 8 * i][l] * cvv;
    }
    #pragma unroll
    for (int i = 0; i < 4; ++i)
        P[((size_t)(j * B_ + b)) * 1024 + (size_t)(g + 8 * i) * R_ + o] = acc[i];
}

// ---------------------------------------------------------------------------
// k_wvec (fp32)
// ---------------------------------------------------------------------------
__global__ __launch_bounds__(256) void k_wvec(const float* __restrict__ V,
                                              const float* __restrict__ P,
                                              float* __restrict__ W2)
{
    const int tid  = threadIdx.x;
    const int m    = blockIdx.y;
    const int tok0 = blockIdx.x * 128;
    const int b    = tok0 / T_;

    __shared__ float Ps[32][32];
    __shared__ float Vs[128][32];

    *(float4*)&(((float*)Ps)[tid * 4]) =
        *(const float4*)&P[((size_t)(m * B_ + b)) * 1024 + tid * 4];

    const int st = tid >> 1, sc = (tid & 1) * 16;
    const float* Vb = V + ((size_t)m * BT_ + tok0) * R_;
    #pragma unroll
    for (int q = 0; q < 4; ++q)
        *(float4*)&Vs[st][sc + q * 4] = *(const float4*)&Vb[(size_t)st * R_ + sc + q * 4];
    __syncthreads();

    const int o = tid & 31, g = tid >> 5;
    float* W2b = W2 + ((size_t)m * BT_ + tok0) * R_;
    #pragma unroll
    for (int i = 0; i < 16; ++i) {
        const int t = g * 16 + i;
        float acc = 0.f;
        #pragma unroll
        for (int l = 0; l < 32; ++l) acc += Vs[t][l] * Ps[l][o];
        W2b[(size_t)t * R_ + o] = acc;
    }
}

// ---------------------------------------------------------------------------
// k_gemm2_mfma: proj = (u ox w) @ Watt via f16 MFMA, A generated in-register.
// Block: 64 tok x 256 cols; 4 waves = (tokg 0/1) x (colg 0/1, 128 cols each).
// K = 1024 = 32 steps of 32 (2 MFMA-K16 each). B streamed frag-major via LDS.
// grid (BT/64, D/256, MODS), block 256
// ---------------------------------------------------------------------------
__global__ __launch_bounds__(256) void k_gemm2_mfma(
    const float* __restrict__ U, const float* __restrict__ W2,
    const uint4* __restrict__ WattF, const float* __restrict__ batt,
    float* __restrict__ X, int li)
{
    __shared__ uint4 sm[2][1024];   // 2 x 16KB
    const int tid = threadIdx.x;
    const int wid = tid>>6, lane = tid&63;
    const int lh = lane>>5, lr = lane&31;
    const int tokg = wid&1, colg = wid>>1;
    const int j = blockIdx.z;
    const int tok0 = blockIdx.x*64;
    const int nbB = blockIdx.y*8;                  // base 32-col block
    const int t = tok0 + tokg*32 + lr;             // A-row token of this lane

    const uint4* src = WattF + (size_t)(li*MODS_ + j)*65536 + (size_t)nbB*128;

    const float* Urow = U  + ((size_t)j*BT_ + t)*R_;
    const float* Wrow = W2 + ((size_t)j*BT_ + t)*R_;
    float u_r[32];
    #pragma unroll
    for (int q=0;q<8;q++){
        float4 t4 = *(const float4*)&Urow[q*4];
        u_r[q*4+0]=t4.x; u_r[q*4+1]=t4.y; u_r[q*4+2]=t4.z; u_r[q*4+3]=t4.w;
    }
    const float4 wa0 = *(const float4*)&Wrow[lh*8];
    const float4 wa1 = *(const float4*)&Wrow[lh*8+4];
    const float4 wb0 = *(const float4*)&Wrow[16+lh*8];
    const float4 wb1 = *(const float4*)&Wrow[16+lh*8+4];

    f32x16 acc[4];
    #pragma unroll
    for (int n=0;n<4;n++){
        #pragma unroll
        for (int i=0;i<16;i++) acc[n][i]=0.f;
    }

    // prologue: stage s=0 (16 KB = 4 issues x 256 thr x 16B)
    #pragma unroll
    for (int it=0;it<4;it++)
        gload_lds16(src + it*256 + tid, &sm[0][it*256 + wid*64]);
    __syncthreads();

    #pragma unroll
    for (int s=0;s<32;s++){
        const int cur = s&1;
        if (s<31){
            const uint4* ssrc = src + (size_t)(s+1)*2048;
            #pragma unroll
            for (int it=0;it<4;it++)
                gload_lds16(ssrc + it*256 + tid, &sm[cur^1][it*256 + wid*64]);
        }
        const float us = u_r[s];
        h8 a0 = mk_h8(us*wa0.x,us*wa0.y,us*wa0.z,us*wa0.w,
                      us*wa1.x,us*wa1.y,us*wa1.z,us*wa1.w);
        h8 a1 = mk_h8(us*wb0.x,us*wb0.y,us*wb0.z,us*wb0.w,
                      us*wb1.x,us*wb1.y,us*wb1.z,us*wb1.w);
        #pragma unroll
        for (int n=0;n<4;n++){
            h8 b0 = __builtin_bit_cast(h8, sm[cur][(colg*4+n)*128 +      lane]);
            h8 b1 = __builtin_bit_cast(h8, sm[cur][(colg*4+n)*128 + 64 + lane]);
            acc[n] = __builtin_amdgcn_mfma_f32_32x32x16_f16(a0, b0, acc[n], 0,0,0);
            acc[n] = __builtin_amdgcn_mfma_f32_32x32x16_f16(a1, b1, acc[n], 0,0,0);
        }
        __syncthreads();
    }

    // epilogue: bias + residual, in-place on X
    const float* battp = batt + (size_t)(li*MODS_ + j)*D_;
    #pragma unroll
    for (int n=0;n<4;n++){
        const int d  = (nbB + colg*4 + n)*32 + lr;
        const float bt = battp[d];
        #pragma unroll
        for (int reg=0; reg<16; ++reg){
            const int row = (reg&3) + 8*(reg>>2) + 4*lh;
            const size_t xi = ((size_t)j*BT_ + tok0 + tokg*32 + row)*D_ + d;
            const float xv = X[xi];
            X[xi] = (acc[n][reg] + bt)*xv + BETA_*xv;
        }
    }
}

// ---------------------------------------------------------------------------
extern "C" void kernel_launch(void* const* d_in, const int* in_sizes, int n_in,
                              void* d_out, int out_size, void* d_ws, size_t ws_size,
                              hipStream_t stream)
{
    const float* x_a  = (const float*)d_in[0];
    const float* x_t  = (const float*)d_in[1];
    const float* x_v  = (const float*)d_in[2];
    const float* Wq1  = (const float*)d_in[3];
    const float* bq1  = (const float*)d_in[4];
    const float* Wq2  = (const float*)d_in[5];
    const float* bq2  = (const float*)d_in[6];
    const float* Wk1  = (const float*)d_in[7];
    const float* bk1  = (const float*)d_in[8];
    const float* Wk2  = (const float*)d_in[9];
    const float* bk2  = (const float*)d_in[10];
    const float* Watt = (const float*)d_in[11];
    const float* batt = (const float*)d_in[12];

    float* X  = (float*)d_out;                       // [3][B*T][D]
    float* U  = (float*)d_ws;                        // [3][BT][R] f32
    float* V  = U  + (size_t)MODS_ * BT_ * R_;
    float* W2 = V  + (size_t)MODS_ * BT_ * R_;
    float* Mq = W2 + (size_t)MODS_ * BT_ * R_;       // [48][1024]
    float* P  = Mq + (size_t)MODS_ * B_ * R_ * R_;   // [48][1024]
    uint4* WattF  = (uint4*)(P + (size_t)MODS_ * B_ * R_ * R_);  // 393216 u4 (6 MB)
    uint4* WprojF = WattF + 393216;                               // 49152 u4 (0.77 MB)

    const size_t modbytes = (size_t)BT_ * D_ * sizeof(float);
    (void)hipMemcpyAsync(X,                        x_a, modbytes, hipMemcpyDeviceToDevice, stream);
    (void)hipMemcpyAsync(X + (size_t)BT_ * D_,     x_t, modbytes, hipMemcpyDeviceToDevice, stream);
    (void)hipMemcpyAsync(X + (size_t)2 * BT_ * D_, x_v, modbytes, hipMemcpyDeviceToDevice, stream);

    k_cvt<<<1728, 256, 0, stream>>>(Watt, Wq1, Wk1, Wq2, Wk2, WattF, WprojF);

    for (int li = 0; li < L_; ++li) {
        k_proj_mfma<<<dim3(BT_/64, MODS_), 256, 0, stream>>>(
            X, WprojF, bq1, bq2, bk1, bk2, U, V, li);
        k_mqk<<<dim3(MODS_ * B_), 256, 0, stream>>>(U, V, Mq);
        k_pmat<<<dim3(MODS_, B_), 256, 0, stream>>>(Mq, P);
        k_wvec<<<dim3(BT_/128, MODS_), 256, 0, stream>>>(V, P, W2);
        k_gemm2_mfma<<<dim3(BT_/64, D_/256, MODS_), 256, 0, stream>>>(
            U, W2, WattF, batt, X, li);
    }
}